// Round 12
// baseline (389.518 us; speedup 1.0000x reference)
//
#include <hip/hip_runtime.h>
#include <hip/hip_bf16.h>
#include <float.h>

#define BATCHES 256
#define NPB     512            // nodes per batch
#define NN      (BATCHES*NPB)  // 131072 total nodes
#define KNN     16
#define KP      17
#define DIN     32
#define DH      128
#define DOUT    8
#define BUFS    24             // phase-2 slots (exact pair thr + slack <= ~20)
#define REVC    96             // reverse capacity: 2-D kNN in-degree bound 6K=96

// ---------------------------------------------------------------- KNN
// (unchanged from R11: 2 thr/node, 4-cand med3 bubble, fast-fma phases,
//  reference-exact final chain + R3-verified canonical merge)
__global__ __launch_bounds__(256) void knn_kernel(
    const float* __restrict__ obs, int* __restrict__ fill, int* __restrict__ rev) {
  __shared__ float4 cand[NPB];                 // {-2x, -2y, sq, -}  8 KiB
  __shared__ unsigned short buf[256 * BUFS];   // 12 KiB
  const int b = blockIdx.x >> 2;               // 4 blocks per batch
  const int quarter = blockIdx.x & 3;
  const int tid = threadIdx.x;
  const int part = tid & 1;
  const int nl = (tid >> 1) + quarter * 128;

  for (int l = tid; l < NPB; l += 256) {
    const float* orow = obs + ((size_t)b * NPB + l) * DIN;
    const float xx = orow[0], yy = orow[1];
    const float sq = __fadd_rn(__fmul_rn(xx, xx), __fmul_rn(yy, yy));
    cand[l] = make_float4(-2.0f * xx, -2.0f * yy, sq, 0.0f);
  }
  __syncthreads();

  const float4 me = cand[nl];
  const float x = -0.5f * me.x;   // exact recovery
  const float y = -0.5f * me.y;
  const float s = me.z;
  const int jbase = part * 256;

  // ---------- phase 1: top-17 fast-d2 values, 4 candidates per pass
  float dl[KP];
#pragma unroll
  for (int t = 0; t < KP; ++t) dl[t] = FLT_MAX;

  for (int jj = 0; jj < 256; jj += 4) {
    const float4 cA = cand[jbase + jj];
    const float4 cB = cand[jbase + jj + 1];
    const float4 cC = cand[jbase + jj + 2];
    const float4 cD = cand[jbase + jj + 3];
    const float dA = __fadd_rn(__fmaf_rn(cA.x, x, __fmaf_rn(cA.y, y, cA.z)), s);
    const float dB = __fadd_rn(__fmaf_rn(cB.x, x, __fmaf_rn(cB.y, y, cB.z)), s);
    const float dC = __fadd_rn(__fmaf_rn(cC.x, x, __fmaf_rn(cC.y, y, cC.z)), s);
    const float dD = __fadd_rn(__fmaf_rn(cD.x, x, __fmaf_rn(cD.y, y, cD.z)), s);
    // sort-4 network
    const float t0 = fminf(dA, dB), t1 = fmaxf(dA, dB);
    const float t2 = fminf(dC, dD), t3 = fmaxf(dC, dD);
    float c0 = fminf(t0, t2);
    const float u1 = fmaxf(t0, t2);
    float c3 = fmaxf(t1, t3);
    const float u2 = fminf(t1, t3);
    float c1 = fminf(u1, u2);
    float c2 = fmaxf(u1, u2);
#pragma unroll
    for (int t = 0; t < KP; ++t) {
      const float d = dl[t];
      const float mn = fminf(d, c0);
      float m0, m1, m2;
      asm("v_med3_f32 %0, %1, %2, %3" : "=v"(m0) : "v"(d), "v"(c0), "v"(c1));
      asm("v_med3_f32 %0, %1, %2, %3" : "=v"(m1) : "v"(d), "v"(c1), "v"(c2));
      asm("v_med3_f32 %0, %1, %2, %3" : "=v"(m2) : "v"(d), "v"(c2), "v"(c3));
      const float mx = fmaxf(d, c3);
      dl[t] = mn;
      c0 = m0; c1 = m1; c2 = m2; c3 = mx;
    }
  }

  // ---------- threshold: 17th-smallest fast-d2 of lane-pair union
  float thr2 = -FLT_MAX;
#pragma unroll
  for (int i = 0; i < KP; ++i) {
    const float ob = __shfl_xor(dl[KP - 1 - i], 1);
    thr2 = fmaxf(thr2, fminf(dl[i], ob));
  }
  const float thrInf = thr2 + 1e-3f;   // absolute slack >= 2x fma error bound

  // ---------- phase 2: collect own candidates (fast d2, superset)
  int cnt = 0;
  const int bufbase = tid * BUFS;
#pragma unroll 2
  for (int jj = 0; jj < 256; ++jj) {
    const int j = jbase + jj;
    const float4 c = cand[j];
    const float d2 = __fadd_rn(__fmaf_rn(c.x, x, __fmaf_rn(c.y, y, c.z)), s);
    if (d2 <= thrInf && cnt < BUFS) {
      buf[bufbase + cnt] = (unsigned short)j;
      ++cnt;
    }
  }

  // ---------- final: exact lex (dist, idx) top-17 of own collected items
  float fd[KP]; int fi[KP];
#pragma unroll
  for (int t = 0; t < KP; ++t) { fd[t] = FLT_MAX; fi[t] = 0x7fffffff; }
  for (int c = 0; c < cnt; ++c) {
    const int j = buf[bufbase + c];
    const float4 pj = cand[j];
    const float px = -0.5f * pj.x;   // exact
    const float py = -0.5f * pj.y;
    const float dot = __fadd_rn(__fmul_rn(x, px), __fmul_rn(y, py));
    const float d2  = __fsub_rn(__fadd_rn(s, pj.z), __fmul_rn(2.0f, dot));
    const float dc  = sqrtf(fmaxf(d2, 0.0f));
    if (dc < fd[KP - 1]) {
      bool shp = true;
#pragma unroll
      for (int t = KP - 1; t >= 1; --t) {
        const bool sh = dc < fd[t - 1];
        const float nd = sh ? fd[t - 1] : (shp ? dc : fd[t]);
        const int   ni = sh ? fi[t - 1] : (shp ? j  : fi[t]);
        fd[t] = nd; fi[t] = ni;
        shp = sh;
      }
      if (shp) { fd[0] = dc; fi[0] = j; }
    }
  }

  // ---------- canonical merge across lane pair (R3-verified)
  float Ad[KP], Bd[KP]; int Ai[KP], Bi[KP];
#pragma unroll
  for (int t = 0; t < KP; ++t) {
    const float o_d = __shfl_xor(fd[t], 1);
    const int   o_i = __shfl_xor(fi[t], 1);
    Ad[t] = part ? o_d : fd[t];
    Ai[t] = part ? o_i : fi[t];
    Bd[t] = part ? fd[t] : o_d;
    Bi[t] = part ? fi[t] : o_i;
  }
  float md[KP]; int mi[KP];
#pragma unroll
  for (int i = 0; i < KP; ++i) {
    const float da = Ad[i], db = Bd[KP - 1 - i];
    const int   ia = Ai[i], ib = Bi[KP - 1 - i];
    const bool aless = (da < db) || (da == db && ia < ib);
    md[i] = aless ? da : db;
    mi[i] = aless ? ia : ib;
  }
  int minpos = 0;
#pragma unroll
  for (int i = 1; i < KP; ++i) {
    const bool less = (md[i] < md[minpos]) ||
                      (md[i] == md[minpos] && mi[i] < mi[minpos]);
    minpos = less ? i : minpos;
  }
  const int src = b * NPB + nl;
#pragma unroll
  for (int i = 0; i < KP; ++i) {
    if ((i & 1) == part && i != minpos) {
      const int g = b * NPB + mi[i];
      const int slot = atomicAdd(&fill[g], 1);
      if (slot < REVC) rev[(size_t)g * REVC + slot] = src;
    }
  }
}

// ------------------------------------------------------------- dinv
__global__ __launch_bounds__(256) void dinv_kernel(
    const int* __restrict__ fill, float* __restrict__ dinv) {
  const int i = blockIdx.x * 256 + threadIdx.x;
  dinv[i] = 1.0f / sqrtf((float)fill[i] + 1.0f);
}

// ---------------------------------------------------- fused GCN layer
// Reassociated: Y = tanh((A_norm . X) @ W + b)   [exact identity with ref]
// NODES nodes/block, 256 threads; TPN = 256/NODES threads per node:
//   4 feature-quarters x ES edge-groups (ES = TPN/4).
// R12 (layer2): NODES=32, ES=2 -> serial edge chain halved, LDS 21 KB ->
//   7 blocks/CU (was 4) for latency hiding. Edge halves combined via
//   __shfl_xor(4) (8-thread node groups never straddle a wave).
// Phase B: GEMM (thread = NODES/8 rows x 4 cols), W staged in 8-k chunks.
// HEAD=true: Wout staged into ws after GEMM; 1 output/thread.
template <int KDIM, bool HEAD, int NODES>
__global__ __launch_bounds__(256) void layer_kernel(
    const float* __restrict__ X, const float* __restrict__ W,
    const float* __restrict__ bias,
    const int* __restrict__ fill, const int* __restrict__ rev,
    const float* __restrict__ dinv,
    const float* __restrict__ Wout, const float* __restrict__ bout,
    float* __restrict__ Y) {
  constexpr int XPAD = (KDIM == 32) ? 36 : 132;   // 16B-aligned rows
  constexpr int TPN  = 256 / NODES;               // threads per node
  constexpr int ES   = TPN / 4;                   // edge split (1 or 2)
  constexpr int NC   = KDIM / 16;                 // float4 chunks per thread
  constexpr int ROWS = NODES / 8;                 // GEMM rows per thread
  __shared__ float xs[NODES][XPAD];
  __shared__ float ws[8][DH];       // 4 KiB W chunk (reused for Wout in HEAD)
  const int tid = threadIdx.x;
  // XCD-bijective swizzle (gridDim.x % 8 == 0): contiguous node ranges/XCD
  const int cpx = gridDim.x >> 3;
  const int blk = (blockIdx.x & 7) * cpx + (blockIdx.x >> 3);
  const int nodeBase = blk * NODES;

  // ---- phase A: aggregate (reassociated)
  {
    const int n  = tid / TPN;
    const int sub = tid % TPN;
    const int p  = sub & 3;           // feature quarter
    const int eh = sub >> 2;          // edge group (0..ES-1)
    const int v = nodeBase + n;
    const float dv = dinv[v];
    float4 a[NC];
    const float wv = dv * dv;
    if (eh == 0) {
#pragma unroll
      for (int c = 0; c < NC; ++c) {
        const float4 xv = *((const float4*)(X + (size_t)v * KDIM) + (p + 4 * c));
        a[c].x = xv.x * wv; a[c].y = xv.y * wv;
        a[c].z = xv.z * wv; a[c].w = xv.w * wv;
      }
    } else {
#pragma unroll
      for (int c = 0; c < NC; ++c) a[c] = make_float4(0.f, 0.f, 0.f, 0.f);
    }
    const int len0 = fill[v];
    const int len = len0 < REVC ? len0 : REVC;
    const size_t beg = (size_t)v * REVC;
    for (int e = eh; e < len; e += ES) {
      const int i = rev[beg + e];
      const float sc = dinv[i] * dv;
#pragma unroll
      for (int c = 0; c < NC; ++c) {
        const float4 xv = *((const float4*)(X + (size_t)i * KDIM) + (p + 4 * c));
        a[c].x += xv.x * sc; a[c].y += xv.y * sc;
        a[c].z += xv.z * sc; a[c].w += xv.w * sc;
      }
    }
    if (ES == 2) {
      // combine edge halves in-register; both end with the full sum
#pragma unroll
      for (int c = 0; c < NC; ++c) {
        a[c].x += __shfl_xor(a[c].x, 4);
        a[c].y += __shfl_xor(a[c].y, 4);
        a[c].z += __shfl_xor(a[c].z, 4);
        a[c].w += __shfl_xor(a[c].w, 4);
      }
      // split the LDS writes between the halves
#pragma unroll
      for (int c = 0; c < NC / 2; ++c) {
        const int cc = eh * (NC / 2) + c;
        *(float4*)&xs[n][4 * (p + 4 * cc)] = a[cc];
      }
    } else {
#pragma unroll
      for (int c = 0; c < NC; ++c)
        *(float4*)&xs[n][4 * (p + 4 * c)] = a[c];
    }
  }
  __syncthreads();

  // ---- phase B: GEMM (rows = nodes, cols = 128 outputs), 8-k chunks
  const int tx = tid & 31;
  const int ty = tid >> 5;
  float acc[ROWS][4] = {};
  for (int kb = 0; kb < KDIM; kb += 8) {
    {
      const int kk = tid >> 5;
      const int cc = (tid & 31) * 4;
      *(float4*)&ws[kk][cc] = *(const float4*)&W[(size_t)(kb + kk) * DH + cc];
    }
    __syncthreads();
#pragma unroll
    for (int k4 = 0; k4 < 2; ++k4) {
      float4 xr[ROWS];
#pragma unroll
      for (int r = 0; r < ROWS; ++r)
        xr[r] = *(const float4*)&xs[ty * ROWS + r][kb + k4 * 4];
#pragma unroll
      for (int kk = 0; kk < 4; ++kk) {
        const float4 w4 = *(const float4*)&ws[k4 * 4 + kk][tx * 4];
#pragma unroll
        for (int r = 0; r < ROWS; ++r) {
          const float a = ((const float*)&xr[r])[kk];
          acc[r][0] += a * w4.x; acc[r][1] += a * w4.y;
          acc[r][2] += a * w4.z; acc[r][3] += a * w4.w;
        }
      }
    }
    __syncthreads();
  }
  const float4 b4 = *(const float4*)&bias[tx * 4];
  float4 t[ROWS];
#pragma unroll
  for (int r = 0; r < ROWS; ++r) {
    t[r].x = tanhf(acc[r][0] + b4.x);
    t[r].y = tanhf(acc[r][1] + b4.y);
    t[r].z = tanhf(acc[r][2] + b4.z);
    t[r].w = tanhf(acc[r][3] + b4.w);
  }

  if (!HEAD) {
#pragma unroll
    for (int r = 0; r < ROWS; ++r)
      *(float4*)&Y[((size_t)nodeBase + ty * ROWS + r) * DH + tx * 4] = t[r];
  } else {
    // stash t into xs; stage Wout into ws (all prior reads barrier-closed)
#pragma unroll
    for (int r = 0; r < ROWS; ++r)
      *(float4*)&xs[ty * ROWS + r][tx * 4] = t[r];
    float* wsf = &ws[0][0];
    ((float4*)wsf)[tid] = ((const float4*)Wout)[tid];   // 1024 floats
    __syncthreads();
    // head: thread -> node tid>>3, output o = tid&7
    const int n2 = tid >> 3;
    const int o = tid & 7;
    float po = 0.0f;
#pragma unroll 8
    for (int k4 = 0; k4 < 32; ++k4) {
      const float4 xv = *(const float4*)&xs[n2][k4 * 4];
      po += xv.x * wsf[(k4 * 4 + 0) * DOUT + o]
          + xv.y * wsf[(k4 * 4 + 1) * DOUT + o]
          + xv.z * wsf[(k4 * 4 + 2) * DOUT + o]
          + xv.w * wsf[(k4 * 4 + 3) * DOUT + o];
    }
    po += bout[o];
    Y[(size_t)(nodeBase + n2) * DOUT + o] = po;
  }
}

// ---------------------------------------------------------------- launch
extern "C" void kernel_launch(void* const* d_in, const int* in_sizes, int n_in,
                              void* d_out, int out_size, void* d_ws, size_t ws_size,
                              hipStream_t stream) {
  const float* obs  = (const float*)d_in[0];
  const float* W1   = (const float*)d_in[1];
  const float* b1   = (const float*)d_in[2];
  const float* W2   = (const float*)d_in[3];
  const float* b2   = (const float*)d_in[4];
  const float* Wout = (const float*)d_in[5];
  const float* bout = (const float*)d_in[6];
  float* out = (float*)d_out;

  char* p = (char*)d_ws;
  auto carve = [&](size_t bytes) {
    void* r = (void*)p;
    p += (bytes + 255) / 256 * 256;
    return r;
  };
  float* x1   = (float*)carve((size_t)NN * DH * 4);       // 67 MB
  int*   rev  = (int*)carve((size_t)NN * REVC * 4);       // 50 MB
  int*   fill = (int*)carve((size_t)NN * 4);
  float* dinv = (float*)carve((size_t)NN * 4);

  hipMemsetAsync(fill, 0, (size_t)NN * 4, stream);

  // graph build: knn + direct reverse-adjacency scatter, then degrees
  knn_kernel<<<BATCHES * 4, 256, 0, stream>>>(obs, fill, rev);
  dinv_kernel<<<NN / 256, 256, 0, stream>>>(fill, dinv);

  // layer 1 (reassociated, fused): x1 = tanh((A.obs) @ W1 + b1)
  layer_kernel<DIN, false, 64><<<NN / 64, 256, 0, stream>>>(
      obs, W1, b1, fill, rev, dinv, nullptr, nullptr, x1);

  // layer 2 + head (fused): out = tanh((A.x1) @ W2 + b2) @ Wout + bout
  layer_kernel<DH, true, 32><<<NN / 32, 256, 0, stream>>>(
      x1, W2, b2, fill, rev, dinv, Wout, bout, out);
}

// Round 13
// 349.474 us; speedup vs baseline: 1.1146x; 1.1146x over previous
//
#include <hip/hip_runtime.h>
#include <hip/hip_bf16.h>
#include <float.h>

#define BATCHES 256
#define NPB     512            // nodes per batch
#define NN      (BATCHES*NPB)  // 131072 total nodes
#define KNN     16
#define KP      17
#define DIN     32
#define DH      128
#define DOUT    8
#define BUFS    24             // phase-2 slots (exact pair thr + slack <= ~20)
#define REVC    96             // reverse capacity: 2-D kNN in-degree bound 6K=96

// ---------------------------------------------------------------- KNN
// (unchanged from R11: 2 thr/node, 4-cand med3 bubble, fast-fma phases,
//  reference-exact final chain + R3-verified canonical merge)
__global__ __launch_bounds__(256) void knn_kernel(
    const float* __restrict__ obs, int* __restrict__ fill, int* __restrict__ rev) {
  __shared__ float4 cand[NPB];                 // {-2x, -2y, sq, -}  8 KiB
  __shared__ unsigned short buf[256 * BUFS];   // 12 KiB
  const int b = blockIdx.x >> 2;               // 4 blocks per batch
  const int quarter = blockIdx.x & 3;
  const int tid = threadIdx.x;
  const int part = tid & 1;
  const int nl = (tid >> 1) + quarter * 128;

  for (int l = tid; l < NPB; l += 256) {
    const float* orow = obs + ((size_t)b * NPB + l) * DIN;
    const float xx = orow[0], yy = orow[1];
    const float sq = __fadd_rn(__fmul_rn(xx, xx), __fmul_rn(yy, yy));
    cand[l] = make_float4(-2.0f * xx, -2.0f * yy, sq, 0.0f);
  }
  __syncthreads();

  const float4 me = cand[nl];
  const float x = -0.5f * me.x;   // exact recovery
  const float y = -0.5f * me.y;
  const float s = me.z;
  const int jbase = part * 256;

  // ---------- phase 1: top-17 fast-d2 values, 4 candidates per pass
  float dl[KP];
#pragma unroll
  for (int t = 0; t < KP; ++t) dl[t] = FLT_MAX;

  for (int jj = 0; jj < 256; jj += 4) {
    const float4 cA = cand[jbase + jj];
    const float4 cB = cand[jbase + jj + 1];
    const float4 cC = cand[jbase + jj + 2];
    const float4 cD = cand[jbase + jj + 3];
    const float dA = __fadd_rn(__fmaf_rn(cA.x, x, __fmaf_rn(cA.y, y, cA.z)), s);
    const float dB = __fadd_rn(__fmaf_rn(cB.x, x, __fmaf_rn(cB.y, y, cB.z)), s);
    const float dC = __fadd_rn(__fmaf_rn(cC.x, x, __fmaf_rn(cC.y, y, cC.z)), s);
    const float dD = __fadd_rn(__fmaf_rn(cD.x, x, __fmaf_rn(cD.y, y, cD.z)), s);
    // sort-4 network
    const float t0 = fminf(dA, dB), t1 = fmaxf(dA, dB);
    const float t2 = fminf(dC, dD), t3 = fmaxf(dC, dD);
    float c0 = fminf(t0, t2);
    const float u1 = fmaxf(t0, t2);
    float c3 = fmaxf(t1, t3);
    const float u2 = fminf(t1, t3);
    float c1 = fminf(u1, u2);
    float c2 = fmaxf(u1, u2);
#pragma unroll
    for (int t = 0; t < KP; ++t) {
      const float d = dl[t];
      const float mn = fminf(d, c0);
      float m0, m1, m2;
      asm("v_med3_f32 %0, %1, %2, %3" : "=v"(m0) : "v"(d), "v"(c0), "v"(c1));
      asm("v_med3_f32 %0, %1, %2, %3" : "=v"(m1) : "v"(d), "v"(c1), "v"(c2));
      asm("v_med3_f32 %0, %1, %2, %3" : "=v"(m2) : "v"(d), "v"(c2), "v"(c3));
      const float mx = fmaxf(d, c3);
      dl[t] = mn;
      c0 = m0; c1 = m1; c2 = m2; c3 = mx;
    }
  }

  // ---------- threshold: 17th-smallest fast-d2 of lane-pair union
  float thr2 = -FLT_MAX;
#pragma unroll
  for (int i = 0; i < KP; ++i) {
    const float ob = __shfl_xor(dl[KP - 1 - i], 1);
    thr2 = fmaxf(thr2, fminf(dl[i], ob));
  }
  const float thrInf = thr2 + 1e-3f;   // absolute slack >= 2x fma error bound

  // ---------- phase 2: collect own candidates (fast d2, superset)
  int cnt = 0;
  const int bufbase = tid * BUFS;
#pragma unroll 2
  for (int jj = 0; jj < 256; ++jj) {
    const int j = jbase + jj;
    const float4 c = cand[j];
    const float d2 = __fadd_rn(__fmaf_rn(c.x, x, __fmaf_rn(c.y, y, c.z)), s);
    if (d2 <= thrInf && cnt < BUFS) {
      buf[bufbase + cnt] = (unsigned short)j;
      ++cnt;
    }
  }

  // ---------- final: exact lex (dist, idx) top-17 of own collected items
  float fd[KP]; int fi[KP];
#pragma unroll
  for (int t = 0; t < KP; ++t) { fd[t] = FLT_MAX; fi[t] = 0x7fffffff; }
  for (int c = 0; c < cnt; ++c) {
    const int j = buf[bufbase + c];
    const float4 pj = cand[j];
    const float px = -0.5f * pj.x;   // exact
    const float py = -0.5f * pj.y;
    const float dot = __fadd_rn(__fmul_rn(x, px), __fmul_rn(y, py));
    const float d2  = __fsub_rn(__fadd_rn(s, pj.z), __fmul_rn(2.0f, dot));
    const float dc  = sqrtf(fmaxf(d2, 0.0f));
    if (dc < fd[KP - 1]) {
      bool shp = true;
#pragma unroll
      for (int t = KP - 1; t >= 1; --t) {
        const bool sh = dc < fd[t - 1];
        const float nd = sh ? fd[t - 1] : (shp ? dc : fd[t]);
        const int   ni = sh ? fi[t - 1] : (shp ? j  : fi[t]);
        fd[t] = nd; fi[t] = ni;
        shp = sh;
      }
      if (shp) { fd[0] = dc; fi[0] = j; }
    }
  }

  // ---------- canonical merge across lane pair (R3-verified)
  float Ad[KP], Bd[KP]; int Ai[KP], Bi[KP];
#pragma unroll
  for (int t = 0; t < KP; ++t) {
    const float o_d = __shfl_xor(fd[t], 1);
    const int   o_i = __shfl_xor(fi[t], 1);
    Ad[t] = part ? o_d : fd[t];
    Ai[t] = part ? o_i : fi[t];
    Bd[t] = part ? fd[t] : o_d;
    Bi[t] = part ? fi[t] : o_i;
  }
  float md[KP]; int mi[KP];
#pragma unroll
  for (int i = 0; i < KP; ++i) {
    const float da = Ad[i], db = Bd[KP - 1 - i];
    const int   ia = Ai[i], ib = Bi[KP - 1 - i];
    const bool aless = (da < db) || (da == db && ia < ib);
    md[i] = aless ? da : db;
    mi[i] = aless ? ia : ib;
  }
  int minpos = 0;
#pragma unroll
  for (int i = 1; i < KP; ++i) {
    const bool less = (md[i] < md[minpos]) ||
                      (md[i] == md[minpos] && mi[i] < mi[minpos]);
    minpos = less ? i : minpos;
  }
  const int src = b * NPB + nl;
#pragma unroll
  for (int i = 0; i < KP; ++i) {
    if ((i & 1) == part && i != minpos) {
      const int g = b * NPB + mi[i];
      const int slot = atomicAdd(&fill[g], 1);
      if (slot < REVC) rev[(size_t)g * REVC + slot] = src;
    }
  }
}

// ------------------------------------------------------------- dinv
__global__ __launch_bounds__(256) void dinv_kernel(
    const int* __restrict__ fill, float* __restrict__ dinv) {
  const int i = blockIdx.x * 256 + threadIdx.x;
  dinv[i] = 1.0f / sqrtf((float)fill[i] + 1.0f);
}

// ---------------------------------------------------- fused GCN layer
// Reassociated: Y = tanh((A_norm . X) @ W + b)   [exact identity with ref]
// NODES nodes/block, 256 threads; TPN = 256/NODES threads per node:
//   4 feature-quarters x ES edge-groups (ES = TPN/4).
// layer2: NODES=32, ES=2 -> serial edge chain halved, LDS 21 KB ->
//   7 blocks/CU for latency hiding. Edge halves combined via
//   __shfl_xor(4) (8-thread node groups never straddle a wave).
// R13 FIX (rule #20): the ES=2 LDS-write split is now a branch on eh with
//   STATICALLY-indexed unrolled loops — R12's a[eh*(NC/2)+c] runtime index
//   demoted a[] to scratch (WRITE_SIZE 4->366 MB, the regression).
// Phase B: GEMM (thread = NODES/8 rows x 4 cols), W staged in 8-k chunks.
// HEAD=true: Wout staged into ws after GEMM; 1 output/thread.
template <int KDIM, bool HEAD, int NODES>
__global__ __launch_bounds__(256) void layer_kernel(
    const float* __restrict__ X, const float* __restrict__ W,
    const float* __restrict__ bias,
    const int* __restrict__ fill, const int* __restrict__ rev,
    const float* __restrict__ dinv,
    const float* __restrict__ Wout, const float* __restrict__ bout,
    float* __restrict__ Y) {
  constexpr int XPAD = (KDIM == 32) ? 36 : 132;   // 16B-aligned rows
  constexpr int TPN  = 256 / NODES;               // threads per node
  constexpr int ES   = TPN / 4;                   // edge split (1 or 2)
  constexpr int NC   = KDIM / 16;                 // float4 chunks per thread
  constexpr int ROWS = NODES / 8;                 // GEMM rows per thread
  __shared__ float xs[NODES][XPAD];
  __shared__ float ws[8][DH];       // 4 KiB W chunk (reused for Wout in HEAD)
  const int tid = threadIdx.x;
  // XCD-bijective swizzle (gridDim.x % 8 == 0): contiguous node ranges/XCD
  const int cpx = gridDim.x >> 3;
  const int blk = (blockIdx.x & 7) * cpx + (blockIdx.x >> 3);
  const int nodeBase = blk * NODES;

  // ---- phase A: aggregate (reassociated)
  {
    const int n  = tid / TPN;
    const int sub = tid % TPN;
    const int p  = sub & 3;           // feature quarter
    const int eh = sub >> 2;          // edge group (0..ES-1)
    const int v = nodeBase + n;
    const float dv = dinv[v];
    float4 a[NC];
    const float wv = dv * dv;
    if (eh == 0) {
#pragma unroll
      for (int c = 0; c < NC; ++c) {
        const float4 xv = *((const float4*)(X + (size_t)v * KDIM) + (p + 4 * c));
        a[c].x = xv.x * wv; a[c].y = xv.y * wv;
        a[c].z = xv.z * wv; a[c].w = xv.w * wv;
      }
    } else {
#pragma unroll
      for (int c = 0; c < NC; ++c) a[c] = make_float4(0.f, 0.f, 0.f, 0.f);
    }
    const int len0 = fill[v];
    const int len = len0 < REVC ? len0 : REVC;
    const size_t beg = (size_t)v * REVC;
    for (int e = eh; e < len; e += ES) {
      const int i = rev[beg + e];
      const float sc = dinv[i] * dv;
#pragma unroll
      for (int c = 0; c < NC; ++c) {
        const float4 xv = *((const float4*)(X + (size_t)i * KDIM) + (p + 4 * c));
        a[c].x += xv.x * sc; a[c].y += xv.y * sc;
        a[c].z += xv.z * sc; a[c].w += xv.w * sc;
      }
    }
    if (ES == 2) {
      // combine edge halves in-register; both end with the full sum
#pragma unroll
      for (int c = 0; c < NC; ++c) {
        a[c].x += __shfl_xor(a[c].x, 4);
        a[c].y += __shfl_xor(a[c].y, 4);
        a[c].z += __shfl_xor(a[c].z, 4);
        a[c].w += __shfl_xor(a[c].w, 4);
      }
      // split LDS writes between the halves — STATIC indices per branch
      if (eh == 0) {
#pragma unroll
        for (int c = 0; c < NC / 2; ++c)
          *(float4*)&xs[n][4 * (p + 4 * c)] = a[c];
      } else {
#pragma unroll
        for (int c = NC / 2; c < NC; ++c)
          *(float4*)&xs[n][4 * (p + 4 * c)] = a[c];
      }
    } else {
#pragma unroll
      for (int c = 0; c < NC; ++c)
        *(float4*)&xs[n][4 * (p + 4 * c)] = a[c];
    }
  }
  __syncthreads();

  // ---- phase B: GEMM (rows = nodes, cols = 128 outputs), 8-k chunks
  const int tx = tid & 31;
  const int ty = tid >> 5;
  float acc[ROWS][4] = {};
  for (int kb = 0; kb < KDIM; kb += 8) {
    {
      const int kk = tid >> 5;
      const int cc = (tid & 31) * 4;
      *(float4*)&ws[kk][cc] = *(const float4*)&W[(size_t)(kb + kk) * DH + cc];
    }
    __syncthreads();
#pragma unroll
    for (int k4 = 0; k4 < 2; ++k4) {
      float4 xr[ROWS];
#pragma unroll
      for (int r = 0; r < ROWS; ++r)
        xr[r] = *(const float4*)&xs[ty * ROWS + r][kb + k4 * 4];
#pragma unroll
      for (int kk = 0; kk < 4; ++kk) {
        const float4 w4 = *(const float4*)&ws[k4 * 4 + kk][tx * 4];
#pragma unroll
        for (int r = 0; r < ROWS; ++r) {
          const float a = ((const float*)&xr[r])[kk];
          acc[r][0] += a * w4.x; acc[r][1] += a * w4.y;
          acc[r][2] += a * w4.z; acc[r][3] += a * w4.w;
        }
      }
    }
    __syncthreads();
  }
  const float4 b4 = *(const float4*)&bias[tx * 4];
  float4 t[ROWS];
#pragma unroll
  for (int r = 0; r < ROWS; ++r) {
    t[r].x = tanhf(acc[r][0] + b4.x);
    t[r].y = tanhf(acc[r][1] + b4.y);
    t[r].z = tanhf(acc[r][2] + b4.z);
    t[r].w = tanhf(acc[r][3] + b4.w);
  }

  if (!HEAD) {
#pragma unroll
    for (int r = 0; r < ROWS; ++r)
      *(float4*)&Y[((size_t)nodeBase + ty * ROWS + r) * DH + tx * 4] = t[r];
  } else {
    // stash t into xs; stage Wout into ws (all prior reads barrier-closed)
#pragma unroll
    for (int r = 0; r < ROWS; ++r)
      *(float4*)&xs[ty * ROWS + r][tx * 4] = t[r];
    float* wsf = &ws[0][0];
    ((float4*)wsf)[tid] = ((const float4*)Wout)[tid];   // 1024 floats
    __syncthreads();
    // head: thread -> node tid>>3, output o = tid&7
    const int n2 = tid >> 3;
    const int o = tid & 7;
    float po = 0.0f;
#pragma unroll 8
    for (int k4 = 0; k4 < 32; ++k4) {
      const float4 xv = *(const float4*)&xs[n2][k4 * 4];
      po += xv.x * wsf[(k4 * 4 + 0) * DOUT + o]
          + xv.y * wsf[(k4 * 4 + 1) * DOUT + o]
          + xv.z * wsf[(k4 * 4 + 2) * DOUT + o]
          + xv.w * wsf[(k4 * 4 + 3) * DOUT + o];
    }
    po += bout[o];
    Y[(size_t)(nodeBase + n2) * DOUT + o] = po;
  }
}

// ---------------------------------------------------------------- launch
extern "C" void kernel_launch(void* const* d_in, const int* in_sizes, int n_in,
                              void* d_out, int out_size, void* d_ws, size_t ws_size,
                              hipStream_t stream) {
  const float* obs  = (const float*)d_in[0];
  const float* W1   = (const float*)d_in[1];
  const float* b1   = (const float*)d_in[2];
  const float* W2   = (const float*)d_in[3];
  const float* b2   = (const float*)d_in[4];
  const float* Wout = (const float*)d_in[5];
  const float* bout = (const float*)d_in[6];
  float* out = (float*)d_out;

  char* p = (char*)d_ws;
  auto carve = [&](size_t bytes) {
    void* r = (void*)p;
    p += (bytes + 255) / 256 * 256;
    return r;
  };
  float* x1   = (float*)carve((size_t)NN * DH * 4);       // 67 MB
  int*   rev  = (int*)carve((size_t)NN * REVC * 4);       // 50 MB
  int*   fill = (int*)carve((size_t)NN * 4);
  float* dinv = (float*)carve((size_t)NN * 4);

  hipMemsetAsync(fill, 0, (size_t)NN * 4, stream);

  // graph build: knn + direct reverse-adjacency scatter, then degrees
  knn_kernel<<<BATCHES * 4, 256, 0, stream>>>(obs, fill, rev);
  dinv_kernel<<<NN / 256, 256, 0, stream>>>(fill, dinv);

  // layer 1 (reassociated, fused): x1 = tanh((A.obs) @ W1 + b1)
  layer_kernel<DIN, false, 64><<<NN / 64, 256, 0, stream>>>(
      obs, W1, b1, fill, rev, dinv, nullptr, nullptr, x1);

  // layer 2 + head (fused): out = tanh((A.x1) @ W2 + b2) @ Wout + bout
  layer_kernel<DH, true, 32><<<NN / 32, 256, 0, stream>>>(
      x1, W2, b2, fill, rev, dinv, Wout, bout, out);
}